// Round 1
// baseline (3052.734 us; speedup 1.0000x reference)
//
#include <hip/hip_runtime.h>
#include <hip/hip_bf16.h>

// ---- problem constants ----
#define BB_   16
#define QQ_   1024
#define CC_   1280
#define LFULL 477
#define CROSS 2048
#define NTOK  200
#define HEADS 20
#define HD    64
#define EHSL  77      // 477 - 200 - 200
#define SCALE_ 0.125f  // 1/sqrt(64)

typedef short bf16x8 __attribute__((ext_vector_type(8)));
typedef float f32x4  __attribute__((ext_vector_type(4)));

__device__ __forceinline__ float bflo(unsigned u){ return __uint_as_float(u << 16); }
__device__ __forceinline__ float bfhi(unsigned u){ return __uint_as_float(u & 0xffff0000u); }
__device__ __forceinline__ unsigned short f2bf(float f){
    unsigned u = __float_as_uint(f);
    return (unsigned short)((u + 0x7fffu + ((u >> 16) & 1u)) >> 16);
}
__device__ __forceinline__ unsigned pack2(float a, float b){
    return (unsigned)f2bf(a) | ((unsigned)f2bf(b) << 16);
}

// ---- fragment loads: A-path either raw-bf16 (ushort) or fp32 (convert on the fly) ----
__device__ __forceinline__ bf16x8 load_frag(const unsigned short* p){
    return *(const bf16x8*)p;                       // 16B aligned by construction
}
__device__ __forceinline__ bf16x8 load_frag(const float* p){
    const float4* q = (const float4*)p;
    float4 f0 = q[0], f1 = q[1];
    union { unsigned u[4]; bf16x8 v; } r;
    r.u[0] = pack2(f0.x, f0.y);
    r.u[1] = pack2(f0.z, f0.w);
    r.u[2] = pack2(f1.x, f1.y);
    r.u[3] = pack2(f1.z, f1.w);
    return r.v;
}
__device__ __forceinline__ void store_out(unsigned short* p, float v){ *p = f2bf(v); }
__device__ __forceinline__ void store_out(float* p, float v){ *p = v; }

// ============================================================================
// GEMM: C[m][n] = sum_k A[m][k] * W[n][k] (+bias[n])
// A rows are mapped: b = m / rpb, r = m % rpb, phys_row = b*bstride + r
// (handles the non-contiguous encoder slices; contiguous: rpb = M, bstride = 0)
// One wave computes a 16x64 tile via 4x mfma_f32_16x16x32_bf16; block = 4 waves
// covering 16 rows x 256 cols. Requires M%16==0, N%256==0... (N%64 per wave,
// grid.x = N/256), K%32==0. All satisfied here.
// ============================================================================
template<typename AT, typename OT>
__global__ __launch_bounds__(256) void gemm_bt(
    const AT* __restrict__ A,
    const unsigned short* __restrict__ W,
    const float* __restrict__ bias,
    OT* __restrict__ C,
    int M, int N, int K, int rpb, int bstride)
{
    const int lane = threadIdx.x & 63;
    const int wave = threadIdx.x >> 6;
    const int quad = lane >> 4;
    const int l16  = lane & 15;
    const int mbase = blockIdx.y * 16;
    const int nbase = blockIdx.x * 256 + wave * 64;

    const int m  = mbase + l16;
    const int bb = m / rpb;
    const int rr = m - bb * rpb;
    const AT* arow = A + ((size_t)bb * bstride + rr) * (size_t)K + quad * 8;

    const unsigned short* wp[4];
    f32x4 acc[4];
    #pragma unroll
    for (int t = 0; t < 4; t++){
        wp[t] = W + (size_t)(nbase + 16 * t + l16) * K + quad * 8;
        acc[t] = (f32x4){0.f, 0.f, 0.f, 0.f};
    }

    for (int k = 0; k < K; k += 32){
        bf16x8 a = load_frag(arow + k);
        #pragma unroll
        for (int t = 0; t < 4; t++){
            bf16x8 bv = load_frag(wp[t] + k);
            acc[t] = __builtin_amdgcn_mfma_f32_16x16x32_bf16(a, bv, acc[t], 0, 0, 0);
        }
    }

    const int row0 = mbase + quad * 4;
    #pragma unroll
    for (int t = 0; t < 4; t++){
        const int col = nbase + 16 * t + l16;
        const float bs = bias ? bias[col] : 0.f;
        #pragma unroll
        for (int r = 0; r < 4; r++){
            float v = acc[t][r] + bs;
            store_out(C + (size_t)(row0 + r) * N + col, v);
        }
    }
}

// ============================================================================
// Fused attention: per (b,h) stage K,V (Lk x 64, bf16) fully in LDS; one
// thread per q row; single-pass softmax (no max-subtract; scores are O(1) in
// magnitude, fminf(.,80) guards). Optionally adds Addin row (residual / main
// attention output) before the bf16 store. In-place safe: each thread owns
// its row for both read(Addin) and write(Out).
// ============================================================================
__global__ __launch_bounds__(256) void attn_kernel(
    const unsigned short* __restrict__ Qb,
    const unsigned short* __restrict__ Kb,
    const unsigned short* __restrict__ Vb,
    const unsigned short* __restrict__ Addin,   // may be null
    unsigned short* __restrict__ Outb,
    int qrows, int Lk)
{
    extern __shared__ uint4 smem4[];
    uint4* sK = smem4;                 // Lk*8 uint4 (Lk rows x 64 bf16)
    uint4* sV = smem4 + (size_t)Lk * 8;

    const int b = blockIdx.x / HEADS;
    const int h = blockIdx.x % HEADS;

    for (int i = threadIdx.x; i < Lk * 8; i += 256){
        const int row = i >> 3, c = i & 7;
        const size_t g = ((size_t)(b * Lk + row)) * CC_ + h * HD;
        sK[i] = ((const uint4*)(Kb + g))[c];
        sV[i] = ((const uint4*)(Vb + g))[c];
    }
    __syncthreads();

    const int r = blockIdx.y * 256 + threadIdx.x;
    if (r >= qrows) return;

    const size_t qg = ((size_t)b * qrows + r) * CC_ + h * HD;
    float qf[64];
    #pragma unroll
    for (int i = 0; i < 8; i++){
        uint4 p = ((const uint4*)(Qb + qg))[i];
        qf[i*8+0] = bflo(p.x); qf[i*8+1] = bfhi(p.x);
        qf[i*8+2] = bflo(p.y); qf[i*8+3] = bfhi(p.y);
        qf[i*8+4] = bflo(p.z); qf[i*8+5] = bfhi(p.z);
        qf[i*8+6] = bflo(p.w); qf[i*8+7] = bfhi(p.w);
    }

    float o[64];
    #pragma unroll
    for (int i = 0; i < 64; i++) o[i] = 0.f;
    float l = 0.f;

    for (int kk = 0; kk < Lk; kk++){
        const uint4* kr = sK + kk * 8;
        float s0 = 0.f, s1 = 0.f, s2 = 0.f, s3 = 0.f;
        #pragma unroll
        for (int i = 0; i < 8; i++){
            uint4 p = kr[i];
            s0 += qf[i*8+0] * bflo(p.x); s1 += qf[i*8+1] * bfhi(p.x);
            s2 += qf[i*8+2] * bflo(p.y); s3 += qf[i*8+3] * bfhi(p.y);
            s0 += qf[i*8+4] * bflo(p.z); s1 += qf[i*8+5] * bfhi(p.z);
            s2 += qf[i*8+6] * bflo(p.w); s3 += qf[i*8+7] * bfhi(p.w);
        }
        float s = ((s0 + s1) + (s2 + s3)) * SCALE_;
        s = fminf(s, 80.f);
        const float w = __expf(s);
        l += w;
        const uint4* vr = sV + kk * 8;
        #pragma unroll
        for (int i = 0; i < 8; i++){
            uint4 p = vr[i];
            o[i*8+0] += w * bflo(p.x); o[i*8+1] += w * bfhi(p.x);
            o[i*8+2] += w * bflo(p.y); o[i*8+3] += w * bfhi(p.y);
            o[i*8+4] += w * bflo(p.z); o[i*8+5] += w * bfhi(p.z);
            o[i*8+6] += w * bflo(p.w); o[i*8+7] += w * bfhi(p.w);
        }
    }

    const float inv = 1.f / l;
    unsigned ow[32];
    #pragma unroll
    for (int i = 0; i < 32; i++){
        float v0 = o[2*i]   * inv;
        float v1 = o[2*i+1] * inv;
        if (Addin){
            unsigned au = ((const unsigned*)(Addin + qg))[i];
            v0 += bflo(au); v1 += bfhi(au);
        }
        ow[i] = pack2(v0, v1);
    }
    uint4* op = (uint4*)(Outb + qg);
    #pragma unroll
    for (int i = 0; i < 8; i++){
        uint4 p; p.x = ow[4*i]; p.y = ow[4*i+1]; p.z = ow[4*i+2]; p.w = ow[4*i+3];
        op[i] = p;
    }
}

// ============================================================================
// fp32 -> bf16 weight conversion, 8 tensors fused in one launch.
// ============================================================================
struct CvtArgs { const float* src[8]; unsigned short* dst[8]; };

__global__ __launch_bounds__(256) void cvt8_kernel(CvtArgs a)
{
    // counts per tensor (elems): wq, wk, wv, wkb, wvb, wkc, wvc, wout
    const unsigned counts[8] = {1638400u, 2621440u, 2621440u, 2621440u,
                                2621440u, 2621440u, 2621440u, 1638400u};
    size_t e = ((size_t)blockIdx.x * 256 + threadIdx.x) * 4;
    unsigned cum = 0;
    #pragma unroll
    for (int j = 0; j < 8; j++){
        unsigned c = counts[j];
        if (e < (size_t)cum + c){
            unsigned off = (unsigned)(e - cum);
            float4 f = *(const float4*)(a.src[j] + off);
            uint2 o;
            o.x = pack2(f.x, f.y);
            o.y = pack2(f.z, f.w);
            *(uint2*)(a.dst[j] + off) = o;
            return;
        }
        cum += c;
    }
}

// ============================================================================
extern "C" void kernel_launch(void* const* d_in, const int* in_sizes, int n_in,
                              void* d_out, int out_size, void* d_ws, size_t ws_size,
                              hipStream_t stream)
{
    const float* hs   = (const float*)d_in[0];   // (16,1024,1280)
    const float* enc  = (const float*)d_in[1];   // (16,477,2048)
    const float* wq   = (const float*)d_in[2];
    const float* wk   = (const float*)d_in[3];
    const float* wv   = (const float*)d_in[4];
    const float* wkb  = (const float*)d_in[5];
    const float* wvb  = (const float*)d_in[6];
    const float* wkc  = (const float*)d_in[7];
    const float* wvc  = (const float*)d_in[8];
    const float* wout = (const float*)d_in[9];
    const float* bout = (const float*)d_in[10];
    float* out = (float*)d_out;

    char* ws = (char*)d_ws;
    size_t off = 0;
    auto alloc = [&](size_t elems) -> unsigned short* {
        unsigned short* p = (unsigned short*)(ws + off);
        off = (off + elems * 2 + 255) & ~(size_t)255;
        return p;
    };
    unsigned short* wq_b   = alloc(1638400);
    unsigned short* wk_b   = alloc(2621440);
    unsigned short* wv_b   = alloc(2621440);
    unsigned short* wkb_b  = alloc(2621440);
    unsigned short* wvb_b  = alloc(2621440);
    unsigned short* wkc_b  = alloc(2621440);
    unsigned short* wvc_b  = alloc(2621440);
    unsigned short* wout_b = alloc(1638400);
    unsigned short* q_proj = alloc((size_t)BB_ * QQ_ * CC_);      // 16384x1280
    unsigned short* k_proj = alloc((size_t)BB_ * EHSL * CC_);     // 1232x1280
    unsigned short* v_proj = alloc((size_t)BB_ * EHSL * CC_);
    unsigned short* box_k  = alloc((size_t)BB_ * NTOK * CC_);     // 3200x1280
    unsigned short* box_v  = alloc((size_t)BB_ * NTOK * CC_);
    unsigned short* cls_k  = alloc((size_t)BB_ * NTOK * CC_);
    unsigned short* cls_v  = alloc((size_t)BB_ * NTOK * CC_);
    unsigned short* out_main = alloc((size_t)BB_ * QQ_ * CC_);

    // 1) weights fp32 -> bf16 (19,005,440 elems / 4 per thread / 256 per block)
    CvtArgs ca;
    ca.src[0] = wq;  ca.dst[0] = wq_b;
    ca.src[1] = wk;  ca.dst[1] = wk_b;
    ca.src[2] = wv;  ca.dst[2] = wv_b;
    ca.src[3] = wkb; ca.dst[3] = wkb_b;
    ca.src[4] = wvb; ca.dst[4] = wvb_b;
    ca.src[5] = wkc; ca.dst[5] = wkc_b;
    ca.src[6] = wvc; ca.dst[6] = wvc_b;
    ca.src[7] = wout; ca.dst[7] = wout_b;
    hipLaunchKernelGGL(cvt8_kernel, dim3(18560), dim3(256), 0, stream, ca);

    // 2) projections (bf16 MFMA, fp32 A converted on the fly)
    // encoder slices: ehs rows [0,77), box rows [77,277), cls rows [277,477)
    hipLaunchKernelGGL((gemm_bt<float, unsigned short>), dim3(5, 77),  dim3(256), 0, stream,
                       enc,                wk_b,  (const float*)nullptr, k_proj, BB_*EHSL, CC_, CROSS, EHSL, LFULL);
    hipLaunchKernelGGL((gemm_bt<float, unsigned short>), dim3(5, 77),  dim3(256), 0, stream,
                       enc,                wv_b,  (const float*)nullptr, v_proj, BB_*EHSL, CC_, CROSS, EHSL, LFULL);
    hipLaunchKernelGGL((gemm_bt<float, unsigned short>), dim3(5, 200), dim3(256), 0, stream,
                       enc + 77*CROSS,     wkb_b, (const float*)nullptr, box_k,  BB_*NTOK, CC_, CROSS, NTOK, LFULL);
    hipLaunchKernelGGL((gemm_bt<float, unsigned short>), dim3(5, 200), dim3(256), 0, stream,
                       enc + 77*CROSS,     wvb_b, (const float*)nullptr, box_v,  BB_*NTOK, CC_, CROSS, NTOK, LFULL);
    hipLaunchKernelGGL((gemm_bt<float, unsigned short>), dim3(5, 200), dim3(256), 0, stream,
                       enc + 277*CROSS,    wkc_b, (const float*)nullptr, cls_k,  BB_*NTOK, CC_, CROSS, NTOK, LFULL);
    hipLaunchKernelGGL((gemm_bt<float, unsigned short>), dim3(5, 200), dim3(256), 0, stream,
                       enc + 277*CROSS,    wvc_b, (const float*)nullptr, cls_v,  BB_*NTOK, CC_, CROSS, NTOK, LFULL);
    hipLaunchKernelGGL((gemm_bt<float, unsigned short>), dim3(5, 1024), dim3(256), 0, stream,
                       hs,                 wq_b,  (const float*)nullptr, q_proj, BB_*QQ_,  CC_, CC_,   BB_*QQ_, 0);

    // 3) cls self-attention updates: box_k += MEA(box_k, cls_k, cls_v); same for box_v
    hipLaunchKernelGGL(attn_kernel, dim3(BB_*HEADS, 1), dim3(256), NTOK*256, stream,
                       box_k, cls_k, cls_v, box_k, box_k, NTOK, NTOK);
    hipLaunchKernelGGL(attn_kernel, dim3(BB_*HEADS, 1), dim3(256), NTOK*256, stream,
                       box_v, cls_k, cls_v, box_v, box_v, NTOK, NTOK);

    // 4) main attention: out_main = MEA(q, k, v)
    hipLaunchKernelGGL(attn_kernel, dim3(BB_*HEADS, 4), dim3(256), EHSL*256, stream,
                       q_proj, k_proj, v_proj, (const unsigned short*)nullptr, out_main, QQ_, EHSL);

    // 5) box attention: out_main += MEA(q, box_k', box_v')
    hipLaunchKernelGGL(attn_kernel, dim3(BB_*HEADS, 4), dim3(256), NTOK*256, stream,
                       q_proj, box_k, box_v, out_main, out_main, QQ_, NTOK);

    // 6) output projection: out = out_main @ w_out^T + b_out (fp32 store)
    hipLaunchKernelGGL((gemm_bt<unsigned short, float>), dim3(5, 1024), dim3(256), 0, stream,
                       out_main, wout_b, bout, out, BB_*QQ_, CC_, CC_, BB_*QQ_, 0);
}

// Round 2
// 1720.715 us; speedup vs baseline: 1.7741x; 1.7741x over previous
//
#include <hip/hip_runtime.h>
#include <hip/hip_bf16.h>

// ---- problem constants ----
#define BB_   16
#define QQ_   1024
#define CC_   1280
#define LFULL 477
#define CROSS 2048
#define NTOK  200
#define HEADS 20
#define HD    64
#define EHSL  77      // 477 - 200 - 200
#define SCALE_ 0.125f  // 1/sqrt(64)

typedef short bf16x8 __attribute__((ext_vector_type(8)));
typedef float f32x4  __attribute__((ext_vector_type(4)));
typedef float f32x2  __attribute__((ext_vector_type(2)));

__device__ __forceinline__ unsigned short f2bf(float f){
    unsigned u = __float_as_uint(f);
    return (unsigned short)((u + 0x7fffu + ((u >> 16) & 1u)) >> 16);
}
__device__ __forceinline__ unsigned pack2(float a, float b){
    return (unsigned)f2bf(a) | ((unsigned)f2bf(b) << 16);
}
__device__ __forceinline__ f32x2 unpk(unsigned u){
    f32x2 r;
    r.x = __uint_as_float(u << 16);
    r.y = __uint_as_float(u & 0xffff0000u);
    return r;
}

__device__ __forceinline__ void store_out(unsigned short* p, float v){ *p = f2bf(v); }
__device__ __forceinline__ void store_out(float* p, float v){ *p = v; }

// async global->LDS 16B copy (dest = wave-uniform base + lane*16)
typedef __attribute__((address_space(3))) char lds_char_t;
typedef __attribute__((address_space(1))) char glb_char_t;
__device__ __forceinline__ void async16(const void* g, void* l){
    __builtin_amdgcn_global_load_lds((const glb_char_t*)g, (lds_char_t*)l, 16, 0, 0);
}

// ============================================================================
// 128x128-tile GEMM (m97 structure): C[m][n] = sum_k A[m][k]*W[n][k] (+bias)
// A,W bf16 row-major K-inner. 256 threads = 4 waves, each computes 64x64
// via 4x4 mfma_f32_16x16x32_bf16. BK=64. LDS layout [kg][row][8] bf16: the
// async-copy dest (base+lane*16) maps linear t=kg*128+row, and ds_read_b128
// fragments are 16B-consecutive within a quad (conflict-cheap).
// A-row mapping phys = (m/rpb)*bstride + m%rpb handles the encoder slices
// (bstride in A rows). N%128==0, K%64==0; M edge clamped on load, masked on
// store.
// ============================================================================
template<typename OT>
__global__ __launch_bounds__(256) void gemm128(
    const unsigned short* __restrict__ A,
    const unsigned short* __restrict__ W,
    const float* __restrict__ bias,
    OT* __restrict__ C,
    int M, int N, int K, int rpb, int bstride)
{
    __shared__ unsigned short sA[8192];   // 8 kg x 128 rows x 8 bf16 = 16 KB
    __shared__ unsigned short sB[8192];

    const int tid  = threadIdx.x;
    const int lane = tid & 63;
    const int wave = tid >> 6;
    const int quad = lane >> 4;
    const int l16  = lane & 15;
    const int wm   = wave >> 1;     // 0..1
    const int wn   = wave & 1;      // 0..1

    const int tm = blockIdx.y * 128;
    const int tn = blockIdx.x * 128;

    const unsigned short* pA[4];
    const unsigned short* pB[4];
    #pragma unroll
    for (int r = 0; r < 4; r++){
        int t = r * 256 + tid;
        int kg = t >> 7, row = t & 127;
        int gm = tm + row; if (gm > M - 1) gm = M - 1;
        int bb = gm / rpb, rr = gm - bb * rpb;
        pA[r] = A + ((size_t)bb * bstride + rr) * (size_t)K + kg * 8;
        pB[r] = W + (size_t)(tn + row) * K + kg * 8;
    }

    f32x4 acc[4][4];
    #pragma unroll
    for (int i = 0; i < 4; i++)
        #pragma unroll
        for (int j = 0; j < 4; j++)
            acc[i][j] = (f32x4){0.f, 0.f, 0.f, 0.f};

    for (int k0 = 0; k0 < K; k0 += 64){
        __syncthreads();   // previous compute done before LDS overwrite
        #pragma unroll
        for (int r = 0; r < 4; r++){
            async16(pA[r], (char*)sA + (r * 256 + wave * 64) * 16);
            async16(pB[r], (char*)sB + (r * 256 + wave * 64) * 16);
            pA[r] += 64;
            pB[r] += 64;
        }
        __syncthreads();   // staging complete (vmcnt(0) + barrier)

        #pragma unroll
        for (int ks = 0; ks < 2; ks++){
            bf16x8 af[4], bv[4];
            #pragma unroll
            for (int s = 0; s < 4; s++){
                af[s] = *(const bf16x8*)(sA + (((ks*4 + quad) * 128) + wm*64 + s*16 + l16) * 8);
                bv[s] = *(const bf16x8*)(sB + (((ks*4 + quad) * 128) + wn*64 + s*16 + l16) * 8);
            }
            #pragma unroll
            for (int i = 0; i < 4; i++)
                #pragma unroll
                for (int j = 0; j < 4; j++)
                    acc[i][j] = __builtin_amdgcn_mfma_f32_16x16x32_bf16(af[i], bv[j], acc[i][j], 0, 0, 0);
        }
    }

    #pragma unroll
    for (int i = 0; i < 4; i++){
        const int r0 = tm + wm*64 + i*16 + quad*4;
        #pragma unroll
        for (int j = 0; j < 4; j++){
            const int col = tn + wn*64 + j*16 + l16;
            const float bs = bias ? bias[col] : 0.f;
            #pragma unroll
            for (int r = 0; r < 4; r++){
                const int row = r0 + r;
                if (row < M) store_out(C + (size_t)row * N + col, acc[i][j][r] + bs);
            }
        }
    }
}

// ============================================================================
// Fused attention with strided/packed KV. Per (b,h) stage K,V (Lk x 64 bf16)
// in LDS; one thread per q row; single-pass softmax (scores O(1), fminf(.,80)
// guard). f32x2 math targets v_pk_fma_f32. Optional residual Add read at the
// output address. In-place safe: each thread owns its row.
// ============================================================================
__global__ __launch_bounds__(256) void attn_kernel(
    const unsigned short* __restrict__ Q,  int qstride, int qcoff,
    const unsigned short* __restrict__ KV, int kvstride, int vcoff,
    const unsigned short* __restrict__ Add,              // may be null
    unsigned short* __restrict__ O,   int ostride, int ocoff,
    int qrows, int Lk)
{
    extern __shared__ uint4 smem4[];
    uint4* sK = smem4;
    uint4* sV = smem4 + (size_t)Lk * 8;

    const int b = blockIdx.x / HEADS;
    const int h = blockIdx.x % HEADS;

    for (int i = threadIdx.x; i < Lk * 8; i += 256){
        const int row = i >> 3, c = i & 7;
        const size_t g = (size_t)(b * Lk + row) * kvstride + h * HD;
        sK[i] = ((const uint4*)(KV + g))[c];
        sV[i] = ((const uint4*)(KV + g + vcoff))[c];
    }
    __syncthreads();

    const int r = blockIdx.y * 256 + threadIdx.x;
    if (r >= qrows) return;

    const size_t qg = (size_t)(b * qrows + r) * qstride + h * HD + qcoff;
    f32x2 qf[32];
    #pragma unroll
    for (int i = 0; i < 8; i++){
        uint4 p = ((const uint4*)(Q + qg))[i];
        qf[i*4+0] = unpk(p.x);
        qf[i*4+1] = unpk(p.y);
        qf[i*4+2] = unpk(p.z);
        qf[i*4+3] = unpk(p.w);
    }

    f32x2 o[32];
    #pragma unroll
    for (int i = 0; i < 32; i++) o[i] = (f32x2){0.f, 0.f};
    float l = 0.f;

    for (int kk = 0; kk < Lk; kk++){
        const uint4* kr = sK + kk * 8;
        f32x2 sa = (f32x2){0.f, 0.f}, sb = (f32x2){0.f, 0.f};
        #pragma unroll
        for (int i = 0; i < 8; i++){
            uint4 p = kr[i];
            sa += qf[i*4+0] * unpk(p.x);
            sb += qf[i*4+1] * unpk(p.y);
            sa += qf[i*4+2] * unpk(p.z);
            sb += qf[i*4+3] * unpk(p.w);
        }
        float s = ((sa.x + sa.y) + (sb.x + sb.y)) * SCALE_;
        s = fminf(s, 80.f);
        const float w = __expf(s);
        l += w;
        const f32x2 w2 = (f32x2){w, w};
        const uint4* vr = sV + kk * 8;
        #pragma unroll
        for (int i = 0; i < 8; i++){
            uint4 p = vr[i];
            o[i*4+0] += w2 * unpk(p.x);
            o[i*4+1] += w2 * unpk(p.y);
            o[i*4+2] += w2 * unpk(p.z);
            o[i*4+3] += w2 * unpk(p.w);
        }
    }

    const float inv = 1.f / l;
    const f32x2 inv2 = (f32x2){inv, inv};
    const size_t og = (size_t)(b * qrows + r) * ostride + h * HD + ocoff;

    unsigned ow[32];
    #pragma unroll
    for (int i = 0; i < 32; i++){
        f32x2 v = o[i] * inv2;
        if (Add){
            unsigned au = ((const unsigned*)(Add + og))[i];
            v += unpk(au);
        }
        ow[i] = pack2(v.x, v.y);
    }
    uint4* op = (uint4*)(O + og);
    #pragma unroll
    for (int i = 0; i < 8; i++){
        uint4 p; p.x = ow[4*i]; p.y = ow[4*i+1]; p.z = ow[4*i+2]; p.w = ow[4*i+3];
        op[i] = p;
    }
}

// ============================================================================
// fp32 -> bf16 conversion, 10 tensors fused (8 weights + hs + enc).
// ============================================================================
struct Cvt10 { const float* src[10]; unsigned short* dst[10]; };

__global__ __launch_bounds__(256) void cvt10_kernel(Cvt10 a)
{
    const unsigned counts[10] = {1638400u, 2621440u, 2621440u, 2621440u,
                                 2621440u, 2621440u, 2621440u, 1638400u,
                                 20971520u, 15630336u};
    size_t e = ((size_t)blockIdx.x * 256 + threadIdx.x) * 4;
    unsigned cum = 0;
    #pragma unroll
    for (int j = 0; j < 10; j++){
        unsigned c = counts[j];
        if (e < (size_t)cum + c){
            unsigned off = (unsigned)(e - cum);
            float4 f = *(const float4*)(a.src[j] + off);
            uint2 o;
            o.x = pack2(f.x, f.y);
            o.y = pack2(f.z, f.w);
            *(uint2*)(a.dst[j] + off) = o;
            return;
        }
        cum += c;
    }
}

// ============================================================================
extern "C" void kernel_launch(void* const* d_in, const int* in_sizes, int n_in,
                              void* d_out, int out_size, void* d_ws, size_t ws_size,
                              hipStream_t stream)
{
    const float* hs   = (const float*)d_in[0];   // (16,1024,1280)
    const float* enc  = (const float*)d_in[1];   // (16,477,2048)
    const float* wq   = (const float*)d_in[2];
    const float* wk   = (const float*)d_in[3];
    const float* wv   = (const float*)d_in[4];
    const float* wkb  = (const float*)d_in[5];
    const float* wvb  = (const float*)d_in[6];
    const float* wkc  = (const float*)d_in[7];
    const float* wvc  = (const float*)d_in[8];
    const float* wout = (const float*)d_in[9];
    const float* bout = (const float*)d_in[10];
    float* out = (float*)d_out;

    char* ws = (char*)d_ws;
    size_t off = 0;
    auto alloc = [&](size_t elems) -> unsigned short* {
        unsigned short* p = (unsigned short*)(ws + off);
        off = (off + elems * 2 + 255) & ~(size_t)255;
        return p;
    };
    // wk_b/wv_b (and box/cls pairs) are contiguous (sizes are multiples of
    // 128 elems, so alloc() inserts no padding) -> each pair is one stacked
    // (2560, 2048) weight for a fused k|v GEMM.
    unsigned short* wq_b   = alloc(1638400);
    unsigned short* wk_b   = alloc(2621440);
    unsigned short* wv_b   = alloc(2621440);
    unsigned short* wkb_b  = alloc(2621440);
    unsigned short* wvb_b  = alloc(2621440);
    unsigned short* wkc_b  = alloc(2621440);
    unsigned short* wvc_b  = alloc(2621440);
    unsigned short* wout_b = alloc(1638400);
    unsigned short* hs_b   = alloc((size_t)BB_ * QQ_ * CC_);        // 16384x1280
    unsigned short* enc_b  = alloc((size_t)BB_ * LFULL * CROSS);    // 16x477x2048
    unsigned short* q_proj = alloc((size_t)BB_ * QQ_ * CC_);        // 16384x1280
    unsigned short* kv     = alloc((size_t)BB_ * EHSL * 2560);      // 1232x2560 (k|v)
    unsigned short* box_kv = alloc((size_t)BB_ * NTOK * 2560);      // 3200x2560
    unsigned short* cls_kv = alloc((size_t)BB_ * NTOK * 2560);
    unsigned short* out_main = alloc((size_t)BB_ * QQ_ * CC_);

    // 1) fp32 -> bf16 for 8 weights + hs + enc (55,607,296 elems / 4 / 256).
    Cvt10 ca;
    ca.src[0] = wq;   ca.dst[0] = wq_b;
    ca.src[1] = wk;   ca.dst[1] = wk_b;
    ca.src[2] = wv;   ca.dst[2] = wv_b;
    ca.src[3] = wkb;  ca.dst[3] = wkb_b;
    ca.src[4] = wvb;  ca.dst[4] = wvb_b;
    ca.src[5] = wkc;  ca.dst[5] = wkc_b;
    ca.src[6] = wvc;  ca.dst[6] = wvc_b;
    ca.src[7] = wout; ca.dst[7] = wout_b;
    ca.src[8] = hs;   ca.dst[8] = hs_b;
    ca.src[9] = enc;  ca.dst[9] = enc_b;
    hipLaunchKernelGGL(cvt10_kernel, dim3(54304), dim3(256), 0, stream, ca);

    // 2) projections. Encoder slices per batch: ehs [0,77), box [77,277), cls [277,477).
    hipLaunchKernelGGL((gemm128<unsigned short>), dim3(20, 10), dim3(256), 0, stream,
                       enc_b,             wk_b,  (const float*)nullptr, kv,
                       BB_*EHSL, 2560, CROSS, EHSL, LFULL);
    hipLaunchKernelGGL((gemm128<unsigned short>), dim3(20, 25), dim3(256), 0, stream,
                       enc_b + 77*CROSS,  wkb_b, (const float*)nullptr, box_kv,
                       BB_*NTOK, 2560, CROSS, NTOK, LFULL);
    hipLaunchKernelGGL((gemm128<unsigned short>), dim3(20, 25), dim3(256), 0, stream,
                       enc_b + 277*CROSS, wkc_b, (const float*)nullptr, cls_kv,
                       BB_*NTOK, 2560, CROSS, NTOK, LFULL);
    hipLaunchKernelGGL((gemm128<unsigned short>), dim3(10, 128), dim3(256), 0, stream,
                       hs_b,              wq_b,  (const float*)nullptr, q_proj,
                       BB_*QQ_, CC_, CC_, BB_*QQ_, 0);

    // 3) cls self-attention (in place on box_kv halves)
    hipLaunchKernelGGL(attn_kernel, dim3(BB_*HEADS, 1), dim3(256), NTOK*256, stream,
                       box_kv, 2560, 0,    cls_kv, 2560, 1280,
                       box_kv, box_kv, 2560, 0, NTOK, NTOK);
    hipLaunchKernelGGL(attn_kernel, dim3(BB_*HEADS, 1), dim3(256), NTOK*256, stream,
                       box_kv, 2560, 1280, cls_kv, 2560, 1280,
                       box_kv, box_kv, 2560, 1280, NTOK, NTOK);

    // 4) main attention: out_main = MEA(q, k, v)
    hipLaunchKernelGGL(attn_kernel, dim3(BB_*HEADS, 4), dim3(256), EHSL*256, stream,
                       q_proj, CC_, 0, kv, 2560, 1280,
                       (const unsigned short*)nullptr, out_main, CC_, 0, QQ_, EHSL);

    // 5) box attention: out_main += MEA(q, box_k', box_v')
    hipLaunchKernelGGL(attn_kernel, dim3(BB_*HEADS, 4), dim3(256), NTOK*256, stream,
                       q_proj, CC_, 0, box_kv, 2560, 1280,
                       out_main, out_main, CC_, 0, QQ_, NTOK);

    // 6) output projection: out = out_main @ w_out^T + b_out (fp32)
    hipLaunchKernelGGL((gemm128<float>), dim3(10, 128), dim3(256), 0, stream,
                       out_main, wout_b, bout, out, BB_*QQ_, CC_, CC_, BB_*QQ_, 0);
}

// Round 3
// 1000.108 us; speedup vs baseline: 3.0524x; 1.7205x over previous
//
#include <hip/hip_runtime.h>
#include <hip/hip_bf16.h>

// ---- problem constants ----
#define BB_   16
#define QQ_   1024
#define CC_   1280
#define LFULL 477
#define CROSS 2048
#define NTOK  200
#define HEADS 20
#define HD    64
#define EHSL  77      // 477 - 200 - 200
#define SCALE_ 0.125f  // 1/sqrt(64)

typedef short bf16x8 __attribute__((ext_vector_type(8)));
typedef float f32x4  __attribute__((ext_vector_type(4)));

__device__ __forceinline__ unsigned short f2bf(float f){
    unsigned u = __float_as_uint(f);
    return (unsigned short)((u + 0x7fffu + ((u >> 16) & 1u)) >> 16);
}
__device__ __forceinline__ unsigned pack2(float a, float b){
    return (unsigned)f2bf(a) | ((unsigned)f2bf(b) << 16);
}
__device__ __forceinline__ float bfu(unsigned short u){
    return __uint_as_float(((unsigned)u) << 16);
}

__device__ __forceinline__ void store_out(unsigned short* p, float v){ *p = f2bf(v); }
__device__ __forceinline__ void store_out(float* p, float v){ *p = v; }

// async global->LDS 16B copy (dest = wave-uniform base + lane*16)
typedef __attribute__((address_space(3))) char lds_char_t;
typedef __attribute__((address_space(1))) char glb_char_t;
__device__ __forceinline__ void async16(const void* g, void* l){
    __builtin_amdgcn_global_load_lds((const glb_char_t*)g, (lds_char_t*)l, 16, 0, 0);
}

// ============================================================================
// 128x128-tile GEMM (m97 structure): C[m][n] = sum_k A[m][k]*W[n][k] (+bias)
// A,W bf16 row-major K-inner. 256 threads = 4 waves, each 64x64 via 4x4
// mfma_f32_16x16x32_bf16. BK=64, LDS [kg][row][8], global_load_lds width=16.
// A-row mapping phys = (m/rpb)*bstride + m%rpb handles the encoder slices.
// ============================================================================
template<typename OT>
__global__ __launch_bounds__(256) void gemm128(
    const unsigned short* __restrict__ A,
    const unsigned short* __restrict__ W,
    const float* __restrict__ bias,
    OT* __restrict__ C,
    int M, int N, int K, int rpb, int bstride)
{
    __shared__ unsigned short sA[8192];   // 16 KB
    __shared__ unsigned short sB[8192];

    const int tid  = threadIdx.x;
    const int lane = tid & 63;
    const int wave = tid >> 6;
    const int quad = lane >> 4;
    const int l16  = lane & 15;
    const int wm   = wave >> 1;
    const int wn   = wave & 1;

    const int tm = blockIdx.y * 128;
    const int tn = blockIdx.x * 128;

    const unsigned short* pA[4];
    const unsigned short* pB[4];
    #pragma unroll
    for (int r = 0; r < 4; r++){
        int t = r * 256 + tid;
        int kg = t >> 7, row = t & 127;
        int gm = tm + row; if (gm > M - 1) gm = M - 1;
        int bb = gm / rpb, rr = gm - bb * rpb;
        pA[r] = A + ((size_t)bb * bstride + rr) * (size_t)K + kg * 8;
        pB[r] = W + (size_t)(tn + row) * K + kg * 8;
    }

    f32x4 acc[4][4];
    #pragma unroll
    for (int i = 0; i < 4; i++)
        #pragma unroll
        for (int j = 0; j < 4; j++)
            acc[i][j] = (f32x4){0.f, 0.f, 0.f, 0.f};

    for (int k0 = 0; k0 < K; k0 += 64){
        __syncthreads();
        #pragma unroll
        for (int r = 0; r < 4; r++){
            async16(pA[r], (char*)sA + (r * 256 + wave * 64) * 16);
            async16(pB[r], (char*)sB + (r * 256 + wave * 64) * 16);
            pA[r] += 64;
            pB[r] += 64;
        }
        __syncthreads();

        #pragma unroll
        for (int ks = 0; ks < 2; ks++){
            bf16x8 af[4], bv[4];
            #pragma unroll
            for (int s = 0; s < 4; s++){
                af[s] = *(const bf16x8*)(sA + (((ks*4 + quad) * 128) + wm*64 + s*16 + l16) * 8);
                bv[s] = *(const bf16x8*)(sB + (((ks*4 + quad) * 128) + wn*64 + s*16 + l16) * 8);
            }
            #pragma unroll
            for (int i = 0; i < 4; i++)
                #pragma unroll
                for (int j = 0; j < 4; j++)
                    acc[i][j] = __builtin_amdgcn_mfma_f32_16x16x32_bf16(af[i], bv[j], acc[i][j], 0, 0, 0);
        }
    }

    #pragma unroll
    for (int i = 0; i < 4; i++){
        const int r0 = tm + wm*64 + i*16 + quad*4;
        #pragma unroll
        for (int j = 0; j < 4; j++){
            const int col = tn + wn*64 + j*16 + l16;
            const float bs = bias ? bias[col] : 0.f;
            #pragma unroll
            for (int r = 0; r < 4; r++){
                const int row = r0 + r;
                if (row < M) store_out(C + (size_t)row * N + col, acc[i][j][r] + bs);
            }
        }
    }
}

// ============================================================================
// MFMA flash attention. Block = 4 waves; each wave owns 16 q-rows (block: 64).
// Per (b,h): stage K (pitch 72) and V^T (pitch vp = nk32*32+8, both give
// 2-way-only bank aliasing) in LDS. Per k32 chunk:
//   S-tiles (2x): mfma(Q-frag, K-rows-as-B) -> C-layout S[q=quad*4+r][k=l16];
//   exp + (kpos<Lk) mask -> P bf16 to wave-private LDS (16x40, A-layout);
//   PV: A=P-frag, B=V^T rows (ds_read_b128); ones-column MFMA accumulates the
//   softmax denominator l for free (no max-subtract: scores are O(1), clamp 80).
// Epilogue: broadcast l from l16==0 lanes via ds_swizzle(0x10), scale, +Add,
// scalar bf16 stores. In-place safe: Q read before staging barrier; each block
// writes only its own q-rows.
// ============================================================================
__global__ __launch_bounds__(256) void mattn(
    const unsigned short* __restrict__ Q,  int qstride, int qcoff,
    const unsigned short* __restrict__ KV, int kvstride, int vcoff,
    const unsigned short* __restrict__ Add,              // may be null
    unsigned short* __restrict__ O,   int ostride, int ocoff,
    int qrows, int Lk)
{
    extern __shared__ __align__(16) unsigned short smem[];
    const int Lkc16 = (Lk + 15) & ~15;
    const int nk32  = (Lk + 31) >> 5;
    const int vp    = nk32 * 32 + 8;

    const int tid  = threadIdx.x;
    const int lane = tid & 63;
    const int wave = tid >> 6;
    const int quad = lane >> 4;
    const int l16  = lane & 15;

    unsigned short* sK  = smem;
    unsigned short* sVT = smem + Lkc16 * 72;
    unsigned short* sP  = sVT + 64 * vp + wave * 640;   // 16 x 40 per wave

    const int b = blockIdx.x / HEADS;
    const int h = blockIdx.x % HEADS;
    const int q0 = blockIdx.y * 64 + wave * 16;

    // Q fragments (A-operand: m=l16, k=quad*8+j), loaded before the barrier
    const int qr = min(q0 + l16, qrows - 1);
    const unsigned short* qp = Q + (size_t)(b * qrows + qr) * qstride + h * HD + qcoff;
    bf16x8 qa0 = *(const bf16x8*)(qp + quad * 8);
    bf16x8 qa1 = *(const bf16x8*)(qp + 32 + quad * 8);

    // stage K rows [0, Lkc16), source row clamped
    for (int t = tid; t < Lkc16 * 8; t += 256){
        int row = t >> 3, c = t & 7;
        int sr = min(row, Lk - 1);
        uint4 val = *(const uint4*)(KV + (size_t)(b * Lk + sr) * kvstride + h * HD + c * 8);
        *(uint4*)(sK + row * 72 + c * 8) = val;
    }
    // stage V transposed: V^T[d][kpos], kpos in [0, nk32*32)
    for (int t = tid; t < nk32 * 32 * 8; t += 256){
        int kp_ = t >> 3, c = t & 7;
        int sr = min(kp_, Lk - 1);
        uint4 val = *(const uint4*)(KV + (size_t)(b * Lk + sr) * kvstride + h * HD + vcoff + c * 8);
        unsigned short* col = sVT + (c * 8) * vp + kp_;
        col[0*vp] = (unsigned short)(val.x & 0xffff);
        col[1*vp] = (unsigned short)(val.x >> 16);
        col[2*vp] = (unsigned short)(val.y & 0xffff);
        col[3*vp] = (unsigned short)(val.y >> 16);
        col[4*vp] = (unsigned short)(val.z & 0xffff);
        col[5*vp] = (unsigned short)(val.z >> 16);
        col[6*vp] = (unsigned short)(val.w & 0xffff);
        col[7*vp] = (unsigned short)(val.w >> 16);
    }
    __syncthreads();

    // ones B-fragment: column n==0 of the l-tile
    union { unsigned short us[8]; bf16x8 v; } onesu;
    {
        unsigned short ov = (l16 == 0) ? (unsigned short)0x3f80 : (unsigned short)0;
        #pragma unroll
        for (int i = 0; i < 8; i++) onesu.us[i] = ov;
    }

    f32x4 oacc[4], lacc;
    #pragma unroll
    for (int i = 0; i < 4; i++) oacc[i] = (f32x4){0.f, 0.f, 0.f, 0.f};
    lacc = (f32x4){0.f, 0.f, 0.f, 0.f};

    for (int kb = 0; kb < nk32; kb++){
        #pragma unroll
        for (int st = 0; st < 2; st++){
            const int kt = kb * 32 + st * 16;
            const int krow = min(kt + l16, Lkc16 - 1);
            const unsigned short* kp = sK + krow * 72 + quad * 8;
            bf16x8 k0 = *(const bf16x8*)(kp);
            bf16x8 k1 = *(const bf16x8*)(kp + 32);
            f32x4 s = (f32x4){0.f, 0.f, 0.f, 0.f};
            s = __builtin_amdgcn_mfma_f32_16x16x32_bf16(qa0, k0, s, 0, 0, 0);
            s = __builtin_amdgcn_mfma_f32_16x16x32_bf16(qa1, k1, s, 0, 0, 0);
            const bool valid = (kt + l16) < Lk;
            #pragma unroll
            for (int r = 0; r < 4; r++){
                float sv = fminf(s[r] * SCALE_, 80.f);
                float w = valid ? __expf(sv) : 0.f;
                sP[(quad * 4 + r) * 40 + st * 16 + l16] = f2bf(w);
            }
        }
        // P fragment (A-operand) — wave-private buffer, lgkmcnt ordering only
        bf16x8 pf = *(const bf16x8*)(sP + l16 * 40 + quad * 8);
        lacc = __builtin_amdgcn_mfma_f32_16x16x32_bf16(pf, onesu.v, lacc, 0, 0, 0);
        #pragma unroll
        for (int dt = 0; dt < 4; dt++){
            bf16x8 vb = *(const bf16x8*)(sVT + (dt * 16 + l16) * vp + kb * 32 + quad * 8);
            oacc[dt] = __builtin_amdgcn_mfma_f32_16x16x32_bf16(pf, vb, oacc[dt], 0, 0, 0);
        }
    }

    // epilogue: broadcast l within each quad from l16==0, normalize, add, store
    #pragma unroll
    for (int r = 0; r < 4; r++){
        int li = __builtin_amdgcn_ds_swizzle(__float_as_int(lacc[r]), 0x0010);
        float inv = __builtin_amdgcn_rcpf(__int_as_float(li));
        const int qrow = q0 + quad * 4 + r;
        if (qrow < qrows){
            const size_t og = (size_t)(b * qrows + qrow) * ostride + h * HD + ocoff;
            #pragma unroll
            for (int dt = 0; dt < 4; dt++){
                float v = oacc[dt][r] * inv;
                if (Add) v += bfu(Add[og + dt * 16 + l16]);
                O[og + dt * 16 + l16] = f2bf(v);
            }
        }
    }
}

// ============================================================================
// fp32 -> bf16 conversion, 10 tensors fused (8 weights + hs + enc).
// ============================================================================
struct Cvt10 { const float* src[10]; unsigned short* dst[10]; };

__global__ __launch_bounds__(256) void cvt10_kernel(Cvt10 a)
{
    const unsigned counts[10] = {1638400u, 2621440u, 2621440u, 2621440u,
                                 2621440u, 2621440u, 2621440u, 1638400u,
                                 20971520u, 15630336u};
    size_t e = ((size_t)blockIdx.x * 256 + threadIdx.x) * 4;
    unsigned cum = 0;
    #pragma unroll
    for (int j = 0; j < 10; j++){
        unsigned c = counts[j];
        if (e < (size_t)cum + c){
            unsigned off = (unsigned)(e - cum);
            float4 f = *(const float4*)(a.src[j] + off);
            uint2 o;
            o.x = pack2(f.x, f.y);
            o.y = pack2(f.z, f.w);
            *(uint2*)(a.dst[j] + off) = o;
            return;
        }
        cum += c;
    }
}

// ============================================================================
extern "C" void kernel_launch(void* const* d_in, const int* in_sizes, int n_in,
                              void* d_out, int out_size, void* d_ws, size_t ws_size,
                              hipStream_t stream)
{
    const float* hs   = (const float*)d_in[0];   // (16,1024,1280)
    const float* enc  = (const float*)d_in[1];   // (16,477,2048)
    const float* wq   = (const float*)d_in[2];
    const float* wk   = (const float*)d_in[3];
    const float* wv   = (const float*)d_in[4];
    const float* wkb  = (const float*)d_in[5];
    const float* wvb  = (const float*)d_in[6];
    const float* wkc  = (const float*)d_in[7];
    const float* wvc  = (const float*)d_in[8];
    const float* wout = (const float*)d_in[9];
    const float* bout = (const float*)d_in[10];
    float* out = (float*)d_out;

    char* ws = (char*)d_ws;
    size_t off = 0;
    auto alloc = [&](size_t elems) -> unsigned short* {
        unsigned short* p = (unsigned short*)(ws + off);
        off = (off + elems * 2 + 255) & ~(size_t)255;
        return p;
    };
    // adjacent k/v weight pairs form stacked (2560, 2048) weights for fused
    // k|v GEMMs (sizes are multiples of 128 elems -> no alloc padding)
    unsigned short* wq_b   = alloc(1638400);
    unsigned short* wk_b   = alloc(2621440);
    unsigned short* wv_b   = alloc(2621440);
    unsigned short* wkb_b  = alloc(2621440);
    unsigned short* wvb_b  = alloc(2621440);
    unsigned short* wkc_b  = alloc(2621440);
    unsigned short* wvc_b  = alloc(2621440);
    unsigned short* wout_b = alloc(1638400);
    unsigned short* hs_b   = alloc((size_t)BB_ * QQ_ * CC_);
    unsigned short* enc_b  = alloc((size_t)BB_ * LFULL * CROSS);
    unsigned short* q_proj = alloc((size_t)BB_ * QQ_ * CC_);
    unsigned short* kv     = alloc((size_t)BB_ * EHSL * 2560);
    unsigned short* box_kv = alloc((size_t)BB_ * NTOK * 2560);
    unsigned short* cls_kv = alloc((size_t)BB_ * NTOK * 2560);
    unsigned short* out_main = alloc((size_t)BB_ * QQ_ * CC_);

    // 1) fp32 -> bf16
    Cvt10 ca;
    ca.src[0] = wq;   ca.dst[0] = wq_b;
    ca.src[1] = wk;   ca.dst[1] = wk_b;
    ca.src[2] = wv;   ca.dst[2] = wv_b;
    ca.src[3] = wkb;  ca.dst[3] = wkb_b;
    ca.src[4] = wvb;  ca.dst[4] = wvb_b;
    ca.src[5] = wkc;  ca.dst[5] = wkc_b;
    ca.src[6] = wvc;  ca.dst[6] = wvc_b;
    ca.src[7] = wout; ca.dst[7] = wout_b;
    ca.src[8] = hs;   ca.dst[8] = hs_b;
    ca.src[9] = enc;  ca.dst[9] = enc_b;
    hipLaunchKernelGGL(cvt10_kernel, dim3(54304), dim3(256), 0, stream, ca);

    // 2) projections (encoder slices per batch: ehs [0,77), box [77,277), cls [277,477))
    hipLaunchKernelGGL((gemm128<unsigned short>), dim3(20, 10), dim3(256), 0, stream,
                       enc_b,             wk_b,  (const float*)nullptr, kv,
                       BB_*EHSL, 2560, CROSS, EHSL, LFULL);
    hipLaunchKernelGGL((gemm128<unsigned short>), dim3(20, 25), dim3(256), 0, stream,
                       enc_b + 77*CROSS,  wkb_b, (const float*)nullptr, box_kv,
                       BB_*NTOK, 2560, CROSS, NTOK, LFULL);
    hipLaunchKernelGGL((gemm128<unsigned short>), dim3(20, 25), dim3(256), 0, stream,
                       enc_b + 277*CROSS, wkc_b, (const float*)nullptr, cls_kv,
                       BB_*NTOK, 2560, CROSS, NTOK, LFULL);
    hipLaunchKernelGGL((gemm128<unsigned short>), dim3(10, 128), dim3(256), 0, stream,
                       hs_b,              wq_b,  (const float*)nullptr, q_proj,
                       BB_*QQ_, CC_, CC_, BB_*QQ_, 0);

    auto attn_lds = [](int Lk) -> size_t {
        int l16r = (Lk + 15) & ~15;
        int n32  = (Lk + 31) >> 5;
        int vp   = n32 * 32 + 8;
        return (size_t)(l16r * 72 + 64 * vp + 4 * 16 * 40) * 2;
    };

    // 3) cls self-attention (in place on box_kv halves)
    hipLaunchKernelGGL(mattn, dim3(BB_*HEADS, 4), dim3(256), attn_lds(NTOK), stream,
                       box_kv, 2560, 0,    cls_kv, 2560, 1280,
                       box_kv, box_kv, 2560, 0, NTOK, NTOK);
    hipLaunchKernelGGL(mattn, dim3(BB_*HEADS, 4), dim3(256), attn_lds(NTOK), stream,
                       box_kv, 2560, 1280, cls_kv, 2560, 1280,
                       box_kv, box_kv, 2560, 1280, NTOK, NTOK);

    // 4) main attention: out_main = MEA(q, k, v)
    hipLaunchKernelGGL(mattn, dim3(BB_*HEADS, 16), dim3(256), attn_lds(EHSL), stream,
                       q_proj, CC_, 0, kv, 2560, 1280,
                       (const unsigned short*)nullptr, out_main, CC_, 0, QQ_, EHSL);

    // 5) box attention: out_main += MEA(q, box_k', box_v')
    hipLaunchKernelGGL(mattn, dim3(BB_*HEADS, 16), dim3(256), attn_lds(NTOK), stream,
                       q_proj, CC_, 0, box_kv, 2560, 1280,
                       out_main, out_main, CC_, 0, QQ_, NTOK);

    // 6) output projection: out = out_main @ w_out^T + b_out (fp32)
    hipLaunchKernelGGL((gemm128<float>), dim3(10, 128), dim3(256), 0, stream,
                       out_main, wout_b, bout, out, BB_*QQ_, CC_, CC_, BB_*QQ_, 0);
}